// Round 6
// baseline (243.339 us; speedup 1.0000x reference)
//
#include <hip/hip_runtime.h>

// Exact-match lookup of 4M int32 queries in a sorted 8M int32 key table.
// Round 6: no hash table. Partition queries into 8192 bins by top 13 bits
// (atomic-cursor scatter), then one block per bin stages the bin's sorted
// key/value window (~1024 keys) in LDS and binary-searches each binned query
// there. Converts 269 MB of random 64B-line reads (3.3 TB/s ceiling) into
// ~180 MB of streaming traffic.
//
// Correctness: every query lands exactly once in {bin slots} U {overflow
// list}; join + overflow kernels together write out[orig_idx] exactly once.
// A query's equal keys all share its bin (same top 13 bits), and LDS
// lower_bound returns the first match -> searchsorted-left semantics.
// Overflow (bin count > CAP) and oversized windows (> WMAX) are handled by
// slow-but-correct fallbacks that statistically never run.

constexpr int NBINS = 8192;   // bins = top 13 bits of query
constexpr int SHIFT = 18;     // bin = (unsigned)q >> 18
constexpr int CAP   = 1024;   // slots/bin (avg load 512; P(overflow) ~ 0)
constexpr int WMAX  = 2048;   // LDS window capacity (avg 1024 keys/bin)

__device__ __forceinline__ int lower_bound_g(const int* __restrict__ keys,
                                             int lo, int hi, unsigned t) {
    while (lo < hi) {
        int m = (lo + hi) >> 1;
        if ((unsigned)keys[m] < t) lo = m + 1; else hi = m;
    }
    return lo;
}

// K1: per-bin key-window index + zero the cursors/overflow counter.
__global__ void index_kernel(const int* __restrict__ keys, int K,
                             int* __restrict__ bstart,
                             int* __restrict__ cursor,
                             int* __restrict__ ovf_count) {
    int i = blockIdx.x * blockDim.x + threadIdx.x;
    if (i <= NBINS) bstart[i] = lower_bound_g(keys, 0, K, ((unsigned)i) << SHIFT);
    if (i < NBINS) cursor[i] = 0;
    if (i == 0) *ovf_count = 0;
}

// K2: scatter (query, orig_idx) into its bin.
__global__ void scatter_kernel(const int* __restrict__ query, int N,
                               int* __restrict__ cursor,
                               int2* __restrict__ pairs,
                               int* __restrict__ ovf_count,
                               int2* __restrict__ ovf) {
    int t = blockIdx.x * blockDim.x + threadIdx.x;
    int i4 = t * 4;
    if (i4 + 3 < N) {
        int4 qv = *reinterpret_cast<const int4*>(query + i4);
        int qs[4] = {qv.x, qv.y, qv.z, qv.w};
#pragma unroll
        for (int k = 0; k < 4; ++k) {
            unsigned q = (unsigned)qs[k];
            int bin = (int)(q >> SHIFT);
            int slot = atomicAdd(&cursor[bin], 1);
            if (slot < CAP) pairs[(size_t)bin * CAP + slot] = make_int2((int)q, i4 + k);
            else { int p = atomicAdd(ovf_count, 1); ovf[p] = make_int2((int)q, i4 + k); }
        }
    } else if (i4 < N) {
        for (int i = i4; i < N; ++i) {
            unsigned q = (unsigned)query[i];
            int bin = (int)(q >> SHIFT);
            int slot = atomicAdd(&cursor[bin], 1);
            if (slot < CAP) pairs[(size_t)bin * CAP + slot] = make_int2((int)q, i);
            else { int p = atomicAdd(ovf_count, 1); ovf[p] = make_int2((int)q, i); }
        }
    }
}

// K3: one block per bin — LDS-staged window, binary search each binned query.
__global__ void __launch_bounds__(256) join_kernel(
        const int* __restrict__ keys, const int* __restrict__ vals, int K,
        const int* __restrict__ bstart, const int* __restrict__ cursor,
        const int2* __restrict__ pairs, int* __restrict__ out) {
    __shared__ unsigned s_keys[WMAX];
    __shared__ int s_vals[WMAX];
    int b = blockIdx.x;
    int wlo = bstart[b], whi = bstart[b + 1];
    int wn = whi - wlo;
    int count = cursor[b];
    if (count > CAP) count = CAP;
    bool use_lds = (wn <= WMAX);  // block-uniform
    if (use_lds) {
        for (int j = threadIdx.x; j < wn; j += 256) {
            s_keys[j] = (unsigned)keys[wlo + j];
            s_vals[j] = vals[wlo + j];
        }
    }
    __syncthreads();

    const int2* bp = pairs + (size_t)b * CAP;
    for (int j = threadIdx.x; j < count; j += 256) {
        int2 p = bp[j];
        unsigned q = (unsigned)p.x;
        int r = -1;
        if (use_lds) {
            int l = 0, h = wn;
            while (l < h) {
                int m = (l + h) >> 1;
                if (s_keys[m] < q) l = m + 1; else h = m;
            }
            if (l < wn && s_keys[l] == q) r = s_vals[l];
        } else {  // statistically-never: window too big for LDS
            int l = lower_bound_g(keys, wlo, whi, q);
            if (l < whi && (unsigned)keys[l] == q) r = vals[l];
        }
        out[p.y] = r;
    }
}

// K4: overflow queries (bin exceeded CAP) — global binary search. ~Never runs.
__global__ void ovf_kernel(const int2* __restrict__ ovf,
                           const int* __restrict__ ovf_count,
                           const int* __restrict__ keys,
                           const int* __restrict__ vals, int K,
                           int* __restrict__ out) {
    int n = *ovf_count;
    for (int i = blockIdx.x * blockDim.x + threadIdx.x; i < n;
         i += gridDim.x * blockDim.x) {
        int2 p = ovf[i];
        unsigned q = (unsigned)p.x;
        int l = lower_bound_g(keys, 0, K, q);
        int r = -1;
        if (l < K && (unsigned)keys[l] == q) r = vals[l];
        out[p.y] = r;
    }
}

// Fallback for tiny workspace: plain binary search per query.
__global__ void lookup_bsearch_kernel(const int* __restrict__ query,
                                      const int* __restrict__ keys,
                                      const int* __restrict__ vals,
                                      int* __restrict__ out,
                                      int N, int K) {
    int i = blockIdx.x * blockDim.x + threadIdx.x;
    if (i >= N) return;
    unsigned q = (unsigned)query[i];
    int lo = lower_bound_g(keys, 0, K, q);
    int r = -1;
    if (lo < K && (unsigned)keys[lo] == q) r = vals[lo];
    out[i] = r;
}

extern "C" void kernel_launch(void* const* d_in, const int* in_sizes, int n_in,
                              void* d_out, int out_size, void* d_ws, size_t ws_size,
                              hipStream_t stream) {
    const int* query = (const int*)d_in[0];
    const int* keys  = (const int*)d_in[1];
    const int* vals  = (const int*)d_in[2];
    int* out = (int*)d_out;
    const int N = in_sizes[0];
    const int K = in_sizes[1];
    const int tb = 256;

    // Workspace layout (all 16B-aligned):
    //   pairs  : NBINS*CAP int2              = 64 MB
    //   bstart : (NBINS+1) int
    //   cursor : NBINS int
    //   ovfcnt : 1 int (padded)
    //   ovf    : N int2                      = 32 MB
    size_t off = 0;
    int2* pairs = (int2*)((char*)d_ws + off);
    off += (size_t)NBINS * CAP * sizeof(int2);
    int* bstart = (int*)((char*)d_ws + off);
    off += ((size_t)(NBINS + 1) * 4 + 15) & ~(size_t)15;
    int* cursor = (int*)((char*)d_ws + off);
    off += ((size_t)NBINS * 4 + 15) & ~(size_t)15;
    int* ovf_count = (int*)((char*)d_ws + off);
    off += 16;
    int2* ovf = (int2*)((char*)d_ws + off);
    off += (size_t)N * sizeof(int2);

    if (off <= ws_size) {
        index_kernel<<<(NBINS + 1 + tb - 1) / tb, tb, 0, stream>>>(
            keys, K, bstart, cursor, ovf_count);
        int nq4 = (N + 3) / 4;
        scatter_kernel<<<(nq4 + tb - 1) / tb, tb, 0, stream>>>(
            query, N, cursor, pairs, ovf_count, ovf);
        join_kernel<<<NBINS, tb, 0, stream>>>(keys, vals, K, bstart, cursor,
                                              pairs, out);
        ovf_kernel<<<64, tb, 0, stream>>>(ovf, ovf_count, keys, vals, K, out);
    } else {
        lookup_bsearch_kernel<<<(N + tb - 1) / tb, tb, 0, stream>>>(query, keys,
                                                                    vals, out, N, K);
    }
}